// Round 14
// baseline (207.708 us; speedup 1.0000x reference)
//
#include <hip/hip_runtime.h>
#include <hip/hip_bf16.h>
#include <math.h>

#define NS 4096      // samples
#define NC 512       // clusters
#define ND 64        // feature dim
#define NK 10        // classes
#define NPAIR 2080   // upper-triangle pairs (e<=d) of 64x64
#define KP 2176      // 2080 + 64 (linear) + 1 (const) + 31 zero-pad; 68*32
#define BOFF 2080
#define KOFF 2144
#define KSPLIT 4
#define KT_PER (KP / 32 / KSPLIT)   // 17 k-chunks per split block
#define ZB 1024                     // d2-zeroing blocks

typedef __attribute__((ext_vector_type(8))) short short8;
typedef __attribute__((ext_vector_type(4))) float floatx4;

__device__ inline unsigned short f2b(float x) {
    __hip_bfloat16 h = __float2bfloat16(x);           // RNE
    return __builtin_bit_cast(unsigned short, h);
}
__device__ inline float b2f(unsigned short u) {
    __hip_bfloat16 h = __builtin_bit_cast(__hip_bfloat16, u);
    return __bfloat162float(h);
}

// async global->LDS, 16B per lane (m97 lever); dst = wave-uniform base + lane*16
__device__ inline void gl16(const void* g, void* l) {
    __builtin_amdgcn_global_load_lds(
        (const __attribute__((address_space(1))) unsigned int*)g,
        (__attribute__((address_space(3))) unsigned int*)l, 16, 0, 0);
}

// ---------------- (e,d) table with sentinels: val[p] = z[e]*z[d] ------------
__global__ void table_kernel(int2* __restrict__ edt) {
    const int e = threadIdx.x;                        // 64 threads
    int off = e * 64 - (e * (e - 1)) / 2;             // row e starts here
    for (int d = e; d < 64; ++d) edt[off + d - e] = make_int2(e, d);
    edt[BOFF + e] = make_int2(e, 64);                 // linear terms: z*1
    if (e == 0) edt[KOFF] = make_int2(64, 64);        // const term: 1
    if (e < KP - KOFF - 1) edt[KOFF + 1 + e] = make_int2(65, 65);   // pad: 0
}

#define FOR16(M) M(0) M(1) M(2) M(3) M(4) M(5) M(6) M(7) \
                 M(8) M(9) M(10) M(11) M(12) M(13) M(14) M(15)

__device__ inline float4 sel4(bool c, float4 a, float4 b) {
    return make_float4(c ? a.x : b.x, c ? a.y : b.y, c ? a.z : b.z, c ? a.w : b.w);
}

// ---------------- prep (Sigma^-1 + beta pack) + d2 zeroing ------------------
// R14 core: the k-loop is pure register dataflow -- NO LDS, NO barriers.
//  * rp = M[k][j] is lane j's OWN register A_j[k]: selected by a 63-cndmask
//    uniform-k tree (solves R3/R7/R8's dynamic-index scratch trap with VALU).
//  * c_i = M[i][k] = __shfl(A_i, k): k is wave-uniform -> v_readlane (no
//    lgkmcnt, no latency chain). R6-R13's LDS publish/read round-trip
//    (~2500 cyc/step measured) is gone entirely.
__global__ __launch_bounds__(256, 1) void prep_kernel(
    const float* __restrict__ S, const float* __restrict__ n,
    const float* __restrict__ mu, const int* __restrict__ clab,
    const int2* __restrict__ edt, unsigned short* __restrict__ Bph,
    unsigned short* __restrict__ Bpl, float* __restrict__ d2,
    float* __restrict__ labf)
{
    __shared__ float smem[ND * (ND + 1) + ND];
    float* __restrict__ AcolS = smem;                 // [64][65] Sinv mirror
    float* __restrict__ cbuf  = smem + ND * (ND + 1); // bvec staging

    if (blockIdx.x >= NC) {                           // ---- d2 zero role ----
        const size_t base = (size_t)(blockIdx.x - NC) * 2048 + threadIdx.x * 8;
        *(float4*)&d2[base]     = make_float4(0.f, 0.f, 0.f, 0.f);
        *(float4*)&d2[base + 4] = make_float4(0.f, 0.f, 0.f, 0.f);
        return;
    }

    if (threadIdx.x >= 64) return;                    // prep: wave 0 only
    const int c = blockIdx.x;
    const int j = threadIdx.x;                        // column owned by this lane

    const float inv_nc = 1.0f / n[c];
    const float* __restrict__ Sc = S + (size_t)c * ND * ND + j;

#define DECL(t) float4 A##t;
    FOR16(DECL)
#undef DECL

#define LOADT(t) {                                                   \
    const float x0 = Sc[(4*t+0)*ND] * inv_nc;                        \
    const float x1 = Sc[(4*t+1)*ND] * inv_nc;                        \
    const float x2 = Sc[(4*t+2)*ND] * inv_nc;                        \
    const float x3 = Sc[(4*t+3)*ND] * inv_nc;                        \
    A##t.x = (4*t+0 == j) ? x0 + 1e-6f : x0;                         \
    A##t.y = (4*t+1 == j) ? x1 + 1e-6f : x1;                         \
    A##t.z = (4*t+2 == j) ? x2 + 1e-6f : x2;                         \
    A##t.w = (4*t+3 == j) ? x3 + 1e-6f : x3; }
    FOR16(LOADT)
#undef LOADT

    for (int k = 0; k < ND; ++k) {
        // rp = A_j[k] = M[k][j] via uniform-k select tree (63 cndmask)
        const int kg = k >> 2;
        const float4 s0 = sel4(kg & 1, A1,  A0);
        const float4 s1 = sel4(kg & 1, A3,  A2);
        const float4 s2 = sel4(kg & 1, A5,  A4);
        const float4 s3 = sel4(kg & 1, A7,  A6);
        const float4 s4 = sel4(kg & 1, A9,  A8);
        const float4 s5 = sel4(kg & 1, A11, A10);
        const float4 s6 = sel4(kg & 1, A13, A12);
        const float4 s7 = sel4(kg & 1, A15, A14);
        const float4 u0 = sel4(kg & 2, s1, s0);
        const float4 u1 = sel4(kg & 2, s3, s2);
        const float4 u2 = sel4(kg & 2, s5, s4);
        const float4 u3 = sel4(kg & 2, s7, s6);
        const float4 v0 = sel4(kg & 4, u1, u0);
        const float4 v1 = sel4(kg & 4, u3, u2);
        const float4 g  = sel4(kg & 8, v1, v0);
        const float e0 = (k & 1) ? g.y : g.x;
        const float e1 = (k & 1) ? g.w : g.z;
        const float rp = (k & 2) ? e1 : e0;           // M[k][j], pre-update

        const float p  = __shfl(rp, k);               // pivot M[k][k] (readlane)
        const float ip = 1.0f / p;
        const float rowk = (j == k) ? ip : rp * ip;   // scaled row-k element
        const float am   = (j == k) ? 0.0f : 1.0f;    // column-k pre-zero

        // c_i = M[i][k] via readlane broadcast (k uniform); update in place
#define CUPD(t) {                                                    \
    const float c0 = __shfl(A##t.x, k);                              \
    const float c1 = __shfl(A##t.y, k);                              \
    const float c2 = __shfl(A##t.z, k);                              \
    const float c3 = __shfl(A##t.w, k);                              \
    const float rx = A##t.x * am - c0 * rowk;                        \
    const float ry = A##t.y * am - c1 * rowk;                        \
    const float rz = A##t.z * am - c2 * rowk;                        \
    const float rw = A##t.w * am - c3 * rowk;                        \
    A##t.x = (4*t+0 == k) ? rowk : rx;                               \
    A##t.y = (4*t+1 == k) ? rowk : ry;                               \
    A##t.z = (4*t+2 == k) ? rowk : rz;                               \
    A##t.w = (4*t+3 == k) ? rowk : rw; }
        FOR16(CUPD)
#undef CUPD
    }

    // mirror Sinv into LDS for the pack gather; fuse y = Sinv*mu
    float y = 0.f;
#define MIR(t) {                                                     \
    *(float4*)&AcolS[j * (ND + 1) + 4*t] = A##t;                     \
    y += A##t.x * mu[c*ND + 4*t]     + A##t.y * mu[c*ND + 4*t + 1]   \
       + A##t.z * mu[c*ND + 4*t + 2] + A##t.w * mu[c*ND + 4*t + 3]; }
    FOR16(MIR)
#undef MIR
    cbuf[j] = -2.0f * y;                              // bvec values
    float kk = mu[c * ND + j] * y;
    #pragma unroll
    for (int off = 32; off > 0; off >>= 1) kk += __shfl_down(kk, off);
    const float kks = __shfl(kk, 0);
    if (j == 0) {
        int lab = 0;
        for (int q = 0; q < NK; ++q) if (clab[c * NK + q] != 0) lab = q;
        labf[c] = (float)lab;
    }
    __builtin_amdgcn_wave_barrier();

    unsigned short* __restrict__ ph = Bph + (size_t)c * KP;
    unsigned short* __restrict__ pl = Bpl + (size_t)c * KP;
    #pragma unroll
    for (int t = 0; t < KP / 64; ++t) {               // 34 iters, p = t*64+j
        const int p = t * 64 + j;
        float val;
        if (p < NPAIR) {
            const int2 ed = edt[p];
            val = (ed.x == ed.y) ? AcolS[ed.x * (ND + 1) + ed.x]
                : (AcolS[ed.y * (ND + 1) + ed.x] + AcolS[ed.x * (ND + 1) + ed.y]);
        } else if (p < KOFF) val = cbuf[p - BOFF];
        else if (p == KOFF)  val = kks;
        else                 val = 0.f;
        const unsigned short h = f2b(val);
        const unsigned short l = f2b(val - b2f(h));
        ph[p] = h;
        pl[p] = l;
    }
}

// ---------------- d2 = Q·Beta^T, Q built on the fly; 64x256 tile, split-K x4 -
// (R13 version, byte-identical: M=64 halves B-staging redundancy; A-tile
// computed in-block from the z-tile; A rows padded to 40 ushorts.)
__global__ __launch_bounds__(256, 2) void gemm_kernel(
    const float* __restrict__ data, const int2* __restrict__ edt,
    const unsigned short* __restrict__ Bph, const unsigned short* __restrict__ Bpl,
    float* __restrict__ d2)
{
    __shared__ float zS[64 * 68];                             // z-tile + sentinels
    __shared__ unsigned short AhS[64 * 40], AlS[64 * 40];     // 5KB each
    __shared__ unsigned short BhS[256 * 32], BlS[256 * 32];   // 16KB each

    const int tid  = threadIdx.x;
    const int lane = tid & 63, w = tid >> 6;
    const int quad = lane >> 4, rlo = lane & 15;
    const int m0 = blockIdx.x * 64;      // sample tile
    const int n0 = blockIdx.y * 256;     // cluster tile
    const int koff0 = blockIdx.z * KT_PER * 32;   // this block's K-slice start

    #pragma unroll
    for (int q = 0; q < 4; ++q) {
        const int f = q * 256 + tid;                  // float4 id
        const int r = f >> 4, c4 = f & 15;
        const float4 v = *(const float4*)&data[(size_t)(m0 + r) * ND + c4 * 4];
        *(float4*)&zS[r * 68 + c4 * 4] = v;
    }
    if (tid < 64) { zS[tid * 68 + 64] = 1.0f; zS[tid * 68 + 65] = 0.0f; }

    const int brow = tid >> 2, bseg = tid & 3;
    const unsigned short* bGh[4];
    const unsigned short* bGl[4];
    unsigned short* bLh[4];
    unsigned short* bLl[4];
    #pragma unroll
    for (int rd = 0; rd < 4; ++rd) {
        const size_t off = (size_t)(n0 + rd * 64 + brow) * KP + bseg * 8 + koff0;
        bGh[rd] = Bph + off;
        bGl[rd] = Bpl + off;
        bLh[rd] = BhS + (rd * 256 + tid) * 8;         // lane*16B contiguous
        bLl[rd] = BlS + (rd * 256 + tid) * 8;
    }

    const int jc = (tid & 15) * 2;                    // cols jc, jc+1
    const int rb = (tid >> 4) * 4;                    // rows rb..rb+3

    floatx4 acc[4][4] = {};
    __syncthreads();                                  // z-tile visible

    for (int kt = 0; kt < KT_PER; ++kt) {
        const int ko = kt * 32;
        if (kt) __syncthreads();                      // frags consumed
        #pragma unroll
        for (int rd = 0; rd < 4; ++rd) {
            gl16(bGh[rd] + ko, bLh[rd]);
            gl16(bGl[rd] + ko, bLl[rd]);
        }
        const int2 ed0 = edt[koff0 + ko + jc];
        const int2 ed1 = edt[koff0 + ko + jc + 1];
        #pragma unroll
        for (int rr = 0; rr < 4; ++rr) {
            const int r = rb + rr;
            const float* zr = &zS[r * 68];
            const float v0 = zr[ed0.x] * zr[ed0.y];
            const float v1 = zr[ed1.x] * zr[ed1.y];
            const unsigned short h0 = f2b(v0), h1 = f2b(v1);
            const unsigned short l0 = f2b(v0 - b2f(h0)), l1 = f2b(v1 - b2f(h1));
            *(unsigned*)&AhS[r * 40 + jc] = (unsigned)h0 | ((unsigned)h1 << 16);
            *(unsigned*)&AlS[r * 40 + jc] = (unsigned)l0 | ((unsigned)l1 << 16);
        }
        __syncthreads();                              // staging + A visible

        short8 ah[4], al[4], bh[4], bl[4];
        #pragma unroll
        for (int i = 0; i < 4; ++i) {
            ah[i] = *(const short8*)&AhS[(i * 16 + rlo) * 40 + quad * 8];
            al[i] = *(const short8*)&AlS[(i * 16 + rlo) * 40 + quad * 8];
        }
        #pragma unroll
        for (int j2 = 0; j2 < 4; ++j2) {
            const int r = w * 64 + j2 * 16 + rlo;
            bh[j2] = *(const short8*)&BhS[r * 32 + quad * 8];
            bl[j2] = *(const short8*)&BlS[r * 32 + quad * 8];
        }
        #pragma unroll
        for (int i = 0; i < 4; ++i)
            #pragma unroll
            for (int j2 = 0; j2 < 4; ++j2) {
                acc[i][j2] = __builtin_amdgcn_mfma_f32_16x16x32_bf16(al[i], bh[j2], acc[i][j2], 0, 0, 0);
                acc[i][j2] = __builtin_amdgcn_mfma_f32_16x16x32_bf16(ah[i], bl[j2], acc[i][j2], 0, 0, 0);
                acc[i][j2] = __builtin_amdgcn_mfma_f32_16x16x32_bf16(ah[i], bh[j2], acc[i][j2], 0, 0, 0);
            }
    }

    // C layout (verified m89): col = lane&15, row = (lane>>4)*4 + reg
    #pragma unroll
    for (int i = 0; i < 4; ++i)
        #pragma unroll
        for (int j2 = 0; j2 < 4; ++j2) {
            const int m = m0 + i * 16 + quad * 4;
            const int nn = n0 + w * 64 + j2 * 16 + rlo;
            #pragma unroll
            for (int r = 0; r < 4; ++r)
                atomicAdd(&d2[(size_t)(m + r) * NC + nn], acc[i][j2][r]);
        }
}

// ---------------- scores / argmaxes: 4 waves/block, one sample per wave -----
__global__ __launch_bounds__(256) void score_kernel(
    const float* __restrict__ d2, const float* __restrict__ labf,
    float* __restrict__ out)
{
    const int s = blockIdx.x * 4 + (threadIdx.x >> 6);
    const int l = threadIdx.x & 63;

    float numer[NK];
    #pragma unroll
    for (int q = 0; q < NK; ++q) numer[q] = 0.f;
    float denom = 0.f, gmax = -1.f;
    int gidx = 0;

    #pragma unroll
    for (int i = 0; i < NC / 256; ++i) {         // float4 per lane, index-ascending
        const int c0 = i * 256 + l * 4;
        const float4 v = *(const float4*)&d2[(size_t)s * NC + c0];
        #pragma unroll
        for (int r = 0; r < 4; ++r) {
            const int c = c0 + r;
            const float G = __expf(-0.5f * ((const float*)&v)[r]);
            denom += G;
            const int lab = (int)labf[c];
            #pragma unroll
            for (int q = 0; q < NK; ++q) numer[q] += (q == lab) ? G : 0.f;
            if (G > gmax) { gmax = G; gidx = c; }   // strict > keeps first index
        }
    }

    #pragma unroll
    for (int off = 32; off > 0; off >>= 1) {
        const float og = __shfl_down(gmax, off);
        const int   oi = __shfl_down(gidx, off);
        if (og > gmax || (og == gmax && oi < gidx)) { gmax = og; gidx = oi; }
        denom += __shfl_down(denom, off);
        #pragma unroll
        for (int q = 0; q < NK; ++q) numer[q] += __shfl_down(numer[q], off);
    }

    if (l == 0) {
        const float inv = 1.0f / (denom + 1e-12f);
        float best = -1.f; int pk = 0;
        #pragma unroll
        for (int q = 0; q < NK; ++q) {
            const float sc = numer[q] * inv;
            out[(size_t)s * NK + q] = sc;
            if (sc > best) { best = sc; pk = q; }
        }
        out[(size_t)NS * NK + s]      = (float)pk;    // pred
        out[(size_t)NS * NK + NS + s] = (float)gidx;  // clusters
    }
}

extern "C" void kernel_launch(void* const* d_in, const int* in_sizes, int n_in,
                              void* d_out, int out_size, void* d_ws, size_t ws_size,
                              hipStream_t stream)
{
    const float* data = (const float*)d_in[0];
    const float* n    = (const float*)d_in[2];
    const float* mu   = (const float*)d_in[3];
    const float* S    = (const float*)d_in[4];
    const int*   clab = (const int*)d_in[5];

    char* w = (char*)d_ws;
    int2* edt = (int2*)(w);                                     //     17,408 B
    unsigned short* Bph = (unsigned short*)(w + 35651584);      //  2,228,224 B
    unsigned short* Bpl = (unsigned short*)(w + 37879808);      //  2,228,224 B
    float* d2   = (float*)(w + 40108032);                       //  8,388,608 B
    float* labf = (float*)(w + 48496640);                       //      2,048 B

    hipLaunchKernelGGL(table_kernel, dim3(1), dim3(64), 0, stream, edt);
    hipLaunchKernelGGL(prep_kernel,  dim3(NC + ZB), dim3(256), 0, stream,
                       S, n, mu, clab, edt, Bph, Bpl, d2, labf);
    hipLaunchKernelGGL(gemm_kernel,  dim3(NS / 64, NC / 256, KSPLIT), dim3(256), 0, stream,
                       data, edt, Bph, Bpl, d2);
    hipLaunchKernelGGL(score_kernel, dim3(NS / 4), dim3(256), 0, stream,
                       d2, labf, (float*)d_out);
}

// Round 15
// 182.128 us; speedup vs baseline: 1.1405x; 1.1405x over previous
//
#include <hip/hip_runtime.h>
#include <hip/hip_bf16.h>
#include <math.h>

#define NS 4096      // samples
#define NC 512       // clusters
#define ND 64        // feature dim
#define NK 10        // classes
#define NPAIR 2080   // upper-triangle pairs (e<=d) of 64x64
#define KP 2176      // 2080 + 64 (linear) + 1 (const) + 31 zero-pad; 68*32
#define BOFF 2080
#define KOFF 2144
#define KSPLIT 4
#define KT_PER (KP / 32 / KSPLIT)   // 17 k-chunks per split block
#define ZB 1024                     // d2-zeroing blocks

typedef __attribute__((ext_vector_type(8))) short short8;
typedef __attribute__((ext_vector_type(4))) float floatx4;

__device__ inline unsigned short f2b(float x) {
    __hip_bfloat16 h = __float2bfloat16(x);           // RNE
    return __builtin_bit_cast(unsigned short, h);
}
__device__ inline float b2f(unsigned short u) {
    __hip_bfloat16 h = __builtin_bit_cast(__hip_bfloat16, u);
    return __bfloat162float(h);
}

// true v_readlane_b32 (lane is a compile-time literal at every use site)
__device__ inline float rlane(float v, int k) {
    return __builtin_bit_cast(float, __builtin_amdgcn_readlane(__builtin_bit_cast(int, v), k));
}

// async global->LDS, 16B per lane (m97 lever); dst = wave-uniform base + lane*16
__device__ inline void gl16(const void* g, void* l) {
    __builtin_amdgcn_global_load_lds(
        (const __attribute__((address_space(1))) unsigned int*)g,
        (__attribute__((address_space(3))) unsigned int*)l, 16, 0, 0);
}

// ---------------- (e,d) table with sentinels: val[p] = z[e]*z[d] ------------
__global__ void table_kernel(int2* __restrict__ edt) {
    const int e = threadIdx.x;                        // 64 threads
    int off = e * 64 - (e * (e - 1)) / 2;             // row e starts here
    for (int d = e; d < 64; ++d) edt[off + d - e] = make_int2(e, d);
    edt[BOFF + e] = make_int2(e, 64);                 // linear terms: z*1
    if (e == 0) edt[KOFF] = make_int2(64, 64);        // const term: 1
    if (e < KP - KOFF - 1) edt[KOFF + 1 + e] = make_int2(65, 65);   // pad: 0
}

#define FOR16(M) M(0) M(1) M(2) M(3) M(4) M(5) M(6) M(7) \
                 M(8) M(9) M(10) M(11) M(12) M(13) M(14) M(15)
#define FOR16K(M, K) M(0,K) M(1,K) M(2,K) M(3,K) M(4,K) M(5,K) M(6,K) M(7,K) \
                     M(8,K) M(9,K) M(10,K) M(11,K) M(12,K) M(13,K) M(14,K) M(15,K)

// ---------------- prep (Sigma^-1 + beta pack) + d2 zeroing ------------------
// R15 core: FULLY UNROLLED k (64 macro steps, k literal everywhere):
//  * rp = M[k][j] is a direct named register component (no select tree);
//  * column broadcast c_i = readlane(A_i, k) -> v_readlane_b32 (VALU->SGPR,
//    no LDS pipe). R14's __shfl lowered to ds_bpermute (64 LDS ops/step) --
//    that was the regression;
//  * (i==k) fixup folds at compile time; only the two j==k selects remain.
// Arithmetic bit-identical to R13/R14 (absmax 0.0 preserved).
__global__ __launch_bounds__(256, 1) void prep_kernel(
    const float* __restrict__ S, const float* __restrict__ n,
    const float* __restrict__ mu, const int* __restrict__ clab,
    const int2* __restrict__ edt, unsigned short* __restrict__ Bph,
    unsigned short* __restrict__ Bpl, float* __restrict__ d2,
    float* __restrict__ labf)
{
    __shared__ float smem[ND * (ND + 1) + ND];
    float* __restrict__ AcolS = smem;                 // [64][65] Sinv mirror
    float* __restrict__ cbuf  = smem + ND * (ND + 1); // bvec staging

    if (blockIdx.x >= NC) {                           // ---- d2 zero role ----
        const size_t base = (size_t)(blockIdx.x - NC) * 2048 + threadIdx.x * 8;
        *(float4*)&d2[base]     = make_float4(0.f, 0.f, 0.f, 0.f);
        *(float4*)&d2[base + 4] = make_float4(0.f, 0.f, 0.f, 0.f);
        return;
    }

    if (threadIdx.x >= 64) return;                    // prep: wave 0 only
    const int c = blockIdx.x;
    const int j = threadIdx.x;                        // column owned by this lane

    const float inv_nc = 1.0f / n[c];
    const float* __restrict__ Sc = S + (size_t)c * ND * ND + j;

#define DECL(t) float4 A##t;
    FOR16(DECL)
#undef DECL

#define LOADT(t) {                                                   \
    const float x0 = Sc[(4*t+0)*ND] * inv_nc;                        \
    const float x1 = Sc[(4*t+1)*ND] * inv_nc;                        \
    const float x2 = Sc[(4*t+2)*ND] * inv_nc;                        \
    const float x3 = Sc[(4*t+3)*ND] * inv_nc;                        \
    A##t.x = (4*t+0 == j) ? x0 + 1e-6f : x0;                         \
    A##t.y = (4*t+1 == j) ? x1 + 1e-6f : x1;                         \
    A##t.z = (4*t+2 == j) ? x2 + 1e-6f : x2;                         \
    A##t.w = (4*t+3 == j) ? x3 + 1e-6f : x3; }
    FOR16(LOADT)
#undef LOADT

    // ---- 64 fully-unrolled GJ steps (k literal) ----
#define UPDR(u, K) {                                                  \
    const float c0 = rlane(A##u.x, K);                                \
    const float c1 = rlane(A##u.y, K);                                \
    const float c2 = rlane(A##u.z, K);                                \
    const float c3 = rlane(A##u.w, K);                                \
    A##u.x = (4*(u)+0 == (K)) ? rowk : A##u.x * am - c0 * rowk;       \
    A##u.y = (4*(u)+1 == (K)) ? rowk : A##u.y * am - c1 * rowk;       \
    A##u.z = (4*(u)+2 == (K)) ? rowk : A##u.z * am - c2 * rowk;       \
    A##u.w = (4*(u)+3 == (K)) ? rowk : A##u.w * am - c3 * rowk;       \
}
#define STEPC(T, C, K) {                                              \
    const float rp = A##T.C;          /* M[k][j]: own register */     \
    const float pv = rlane(rp, K);    /* pivot M[k][k] */             \
    const float ip = 1.0f / pv;                                       \
    const float rowk = (j == (K)) ? ip : rp * ip;                     \
    const float am   = (j == (K)) ? 0.0f : 1.0f;                      \
    FOR16K(UPDR, K)                                                   \
}
#define STEP4(T) STEPC(T, x, 4*T+0) STEPC(T, y, 4*T+1) \
                 STEPC(T, z, 4*T+2) STEPC(T, w, 4*T+3)
    FOR16(STEP4)
#undef STEP4
#undef STEPC
#undef UPDR

    // mirror Sinv into LDS for the pack gather; fuse y = Sinv*mu
    float y = 0.f;
#define MIR(t) {                                                     \
    *(float4*)&AcolS[j * (ND + 1) + 4*t] = A##t;                     \
    y += A##t.x * mu[c*ND + 4*t]     + A##t.y * mu[c*ND + 4*t + 1]   \
       + A##t.z * mu[c*ND + 4*t + 2] + A##t.w * mu[c*ND + 4*t + 3]; }
    FOR16(MIR)
#undef MIR
    cbuf[j] = -2.0f * y;                              // bvec values
    float kk = mu[c * ND + j] * y;
    #pragma unroll
    for (int off = 32; off > 0; off >>= 1) kk += __shfl_down(kk, off);
    const float kks = __shfl(kk, 0);
    if (j == 0) {
        int lab = 0;
        for (int q = 0; q < NK; ++q) if (clab[c * NK + q] != 0) lab = q;
        labf[c] = (float)lab;
    }
    __builtin_amdgcn_wave_barrier();

    unsigned short* __restrict__ ph = Bph + (size_t)c * KP;
    unsigned short* __restrict__ pl = Bpl + (size_t)c * KP;
    #pragma unroll
    for (int t = 0; t < KP / 64; ++t) {               // 34 iters, p = t*64+j
        const int p = t * 64 + j;
        float val;
        if (p < NPAIR) {
            const int2 ed = edt[p];
            val = (ed.x == ed.y) ? AcolS[ed.x * (ND + 1) + ed.x]
                : (AcolS[ed.y * (ND + 1) + ed.x] + AcolS[ed.x * (ND + 1) + ed.y]);
        } else if (p < KOFF) val = cbuf[p - BOFF];
        else if (p == KOFF)  val = kks;
        else                 val = 0.f;
        const unsigned short h = f2b(val);
        const unsigned short l = f2b(val - b2f(h));
        ph[p] = h;
        pl[p] = l;
    }
}

// ---------------- d2 = Q·Beta^T, Q built on the fly; 64x256 tile, split-K x4 -
// (R13 version, byte-identical.)
__global__ __launch_bounds__(256, 2) void gemm_kernel(
    const float* __restrict__ data, const int2* __restrict__ edt,
    const unsigned short* __restrict__ Bph, const unsigned short* __restrict__ Bpl,
    float* __restrict__ d2)
{
    __shared__ float zS[64 * 68];                             // z-tile + sentinels
    __shared__ unsigned short AhS[64 * 40], AlS[64 * 40];     // 5KB each
    __shared__ unsigned short BhS[256 * 32], BlS[256 * 32];   // 16KB each

    const int tid  = threadIdx.x;
    const int lane = tid & 63, w = tid >> 6;
    const int quad = lane >> 4, rlo = lane & 15;
    const int m0 = blockIdx.x * 64;      // sample tile
    const int n0 = blockIdx.y * 256;     // cluster tile
    const int koff0 = blockIdx.z * KT_PER * 32;   // this block's K-slice start

    #pragma unroll
    for (int q = 0; q < 4; ++q) {
        const int f = q * 256 + tid;                  // float4 id
        const int r = f >> 4, c4 = f & 15;
        const float4 v = *(const float4*)&data[(size_t)(m0 + r) * ND + c4 * 4];
        *(float4*)&zS[r * 68 + c4 * 4] = v;
    }
    if (tid < 64) { zS[tid * 68 + 64] = 1.0f; zS[tid * 68 + 65] = 0.0f; }

    const int brow = tid >> 2, bseg = tid & 3;
    const unsigned short* bGh[4];
    const unsigned short* bGl[4];
    unsigned short* bLh[4];
    unsigned short* bLl[4];
    #pragma unroll
    for (int rd = 0; rd < 4; ++rd) {
        const size_t off = (size_t)(n0 + rd * 64 + brow) * KP + bseg * 8 + koff0;
        bGh[rd] = Bph + off;
        bGl[rd] = Bpl + off;
        bLh[rd] = BhS + (rd * 256 + tid) * 8;         // lane*16B contiguous
        bLl[rd] = BlS + (rd * 256 + tid) * 8;
    }

    const int jc = (tid & 15) * 2;                    // cols jc, jc+1
    const int rb = (tid >> 4) * 4;                    // rows rb..rb+3

    floatx4 acc[4][4] = {};
    __syncthreads();                                  // z-tile visible

    for (int kt = 0; kt < KT_PER; ++kt) {
        const int ko = kt * 32;
        if (kt) __syncthreads();                      // frags consumed
        #pragma unroll
        for (int rd = 0; rd < 4; ++rd) {
            gl16(bGh[rd] + ko, bLh[rd]);
            gl16(bGl[rd] + ko, bLl[rd]);
        }
        const int2 ed0 = edt[koff0 + ko + jc];
        const int2 ed1 = edt[koff0 + ko + jc + 1];
        #pragma unroll
        for (int rr = 0; rr < 4; ++rr) {
            const int r = rb + rr;
            const float* zr = &zS[r * 68];
            const float v0 = zr[ed0.x] * zr[ed0.y];
            const float v1 = zr[ed1.x] * zr[ed1.y];
            const unsigned short h0 = f2b(v0), h1 = f2b(v1);
            const unsigned short l0 = f2b(v0 - b2f(h0)), l1 = f2b(v1 - b2f(h1));
            *(unsigned*)&AhS[r * 40 + jc] = (unsigned)h0 | ((unsigned)h1 << 16);
            *(unsigned*)&AlS[r * 40 + jc] = (unsigned)l0 | ((unsigned)l1 << 16);
        }
        __syncthreads();                              // staging + A visible

        short8 ah[4], al[4], bh[4], bl[4];
        #pragma unroll
        for (int i = 0; i < 4; ++i) {
            ah[i] = *(const short8*)&AhS[(i * 16 + rlo) * 40 + quad * 8];
            al[i] = *(const short8*)&AlS[(i * 16 + rlo) * 40 + quad * 8];
        }
        #pragma unroll
        for (int j2 = 0; j2 < 4; ++j2) {
            const int r = w * 64 + j2 * 16 + rlo;
            bh[j2] = *(const short8*)&BhS[r * 32 + quad * 8];
            bl[j2] = *(const short8*)&BlS[r * 32 + quad * 8];
        }
        #pragma unroll
        for (int i = 0; i < 4; ++i)
            #pragma unroll
            for (int j2 = 0; j2 < 4; ++j2) {
                acc[i][j2] = __builtin_amdgcn_mfma_f32_16x16x32_bf16(al[i], bh[j2], acc[i][j2], 0, 0, 0);
                acc[i][j2] = __builtin_amdgcn_mfma_f32_16x16x32_bf16(ah[i], bl[j2], acc[i][j2], 0, 0, 0);
                acc[i][j2] = __builtin_amdgcn_mfma_f32_16x16x32_bf16(ah[i], bh[j2], acc[i][j2], 0, 0, 0);
            }
    }

    // C layout (verified m89): col = lane&15, row = (lane>>4)*4 + reg
    #pragma unroll
    for (int i = 0; i < 4; ++i)
        #pragma unroll
        for (int j2 = 0; j2 < 4; ++j2) {
            const int m = m0 + i * 16 + quad * 4;
            const int nn = n0 + w * 64 + j2 * 16 + rlo;
            #pragma unroll
            for (int r = 0; r < 4; ++r)
                atomicAdd(&d2[(size_t)(m + r) * NC + nn], acc[i][j2][r]);
        }
}

// ---------------- scores / argmaxes: 4 waves/block, one sample per wave -----
__global__ __launch_bounds__(256) void score_kernel(
    const float* __restrict__ d2, const float* __restrict__ labf,
    float* __restrict__ out)
{
    const int s = blockIdx.x * 4 + (threadIdx.x >> 6);
    const int l = threadIdx.x & 63;

    float numer[NK];
    #pragma unroll
    for (int q = 0; q < NK; ++q) numer[q] = 0.f;
    float denom = 0.f, gmax = -1.f;
    int gidx = 0;

    #pragma unroll
    for (int i = 0; i < NC / 256; ++i) {         // float4 per lane, index-ascending
        const int c0 = i * 256 + l * 4;
        const float4 v = *(const float4*)&d2[(size_t)s * NC + c0];
        #pragma unroll
        for (int r = 0; r < 4; ++r) {
            const int c = c0 + r;
            const float G = __expf(-0.5f * ((const float*)&v)[r]);
            denom += G;
            const int lab = (int)labf[c];
            #pragma unroll
            for (int q = 0; q < NK; ++q) numer[q] += (q == lab) ? G : 0.f;
            if (G > gmax) { gmax = G; gidx = c; }   // strict > keeps first index
        }
    }

    #pragma unroll
    for (int off = 32; off > 0; off >>= 1) {
        const float og = __shfl_down(gmax, off);
        const int   oi = __shfl_down(gidx, off);
        if (og > gmax || (og == gmax && oi < gidx)) { gmax = og; gidx = oi; }
        denom += __shfl_down(denom, off);
        #pragma unroll
        for (int q = 0; q < NK; ++q) numer[q] += __shfl_down(numer[q], off);
    }

    if (l == 0) {
        const float inv = 1.0f / (denom + 1e-12f);
        float best = -1.f; int pk = 0;
        #pragma unroll
        for (int q = 0; q < NK; ++q) {
            const float sc = numer[q] * inv;
            out[(size_t)s * NK + q] = sc;
            if (sc > best) { best = sc; pk = q; }
        }
        out[(size_t)NS * NK + s]      = (float)pk;    // pred
        out[(size_t)NS * NK + NS + s] = (float)gidx;  // clusters
    }
}

extern "C" void kernel_launch(void* const* d_in, const int* in_sizes, int n_in,
                              void* d_out, int out_size, void* d_ws, size_t ws_size,
                              hipStream_t stream)
{
    const float* data = (const float*)d_in[0];
    const float* n    = (const float*)d_in[2];
    const float* mu   = (const float*)d_in[3];
    const float* S    = (const float*)d_in[4];
    const int*   clab = (const int*)d_in[5];

    char* w = (char*)d_ws;
    int2* edt = (int2*)(w);                                     //     17,408 B
    unsigned short* Bph = (unsigned short*)(w + 35651584);      //  2,228,224 B
    unsigned short* Bpl = (unsigned short*)(w + 37879808);      //  2,228,224 B
    float* d2   = (float*)(w + 40108032);                       //  8,388,608 B
    float* labf = (float*)(w + 48496640);                       //      2,048 B

    hipLaunchKernelGGL(table_kernel, dim3(1), dim3(64), 0, stream, edt);
    hipLaunchKernelGGL(prep_kernel,  dim3(NC + ZB), dim3(256), 0, stream,
                       S, n, mu, clab, edt, Bph, Bpl, d2, labf);
    hipLaunchKernelGGL(gemm_kernel,  dim3(NS / 64, NC / 256, KSPLIT), dim3(256), 0, stream,
                       data, edt, Bph, Bpl, d2);
    hipLaunchKernelGGL(score_kernel, dim3(NS / 4), dim3(256), 0, stream,
                       d2, labf, (float*)d_out);
}